// Round 13
// baseline (248.751 us; speedup 1.0000x reference)
//
#include <hip/hip_runtime.h>
#include <hip/hip_bf16.h>

// SelfAttentionMasked: B=4, N=2048, DIM=1024, H=16, DH=64
// k_prep (cvt(x) + transpose_cvt(Wqkv,Wout) + packmask, one dispatch)
// -> QKV GEMM (gload_lds+swizzle, LDS-restaged coalesced epilogue, Q pre-scaled by
// 0.125*log2e) -> flash attn (16x16 swapped QK^T, key-half pipeline, single-buffered
// V + counted mid-tile join, 2x-unrolled kt with STATIC buffer bases) -> out GEMM

typedef __attribute__((ext_vector_type(8))) short bf16x8;
typedef __attribute__((ext_vector_type(4))) float f32x4;

__device__ __forceinline__ unsigned short f2bf(float f) {
  unsigned u = __builtin_bit_cast(unsigned, f);
  u += 0x7fffu + ((u >> 16) & 1u);   // RNE
  return (unsigned short)(u >> 16);
}

// async global->LDS, 16B per lane; LDS dest linear (wave-uniform base + lane*16)
__device__ __forceinline__ void gload16(const void* g, void* l) {
  __builtin_amdgcn_global_load_lds(
      (const __attribute__((address_space(1))) unsigned int*)g,
      (__attribute__((address_space(3))) unsigned int*)l, 16, 0, 0);
}

// swizzled b128 read from a [rows][64-elem] linear LDS tile staged with
// source-byte ^= ((row&7)<<4). elem must be a multiple of 8.
__device__ __forceinline__ bf16x8 ldsw(const short* base, int row, int elem) {
  const char* p = (const char*)base + row * 128 + ((elem * 2) ^ ((row & 7) << 4));
  return *(const bf16x8*)p;
}

// ---------------- fused prep: cvt(x) | transpose_cvt(Wqkv) | transpose_cvt(Wout)
// ---------------- | packmask.  All independent; branch on blockIdx range.
__global__ __launch_bounds__(256) void k_prep(
    const float* __restrict__ x, unsigned short* __restrict__ Xb,
    const float* __restrict__ Wqkv, unsigned short* __restrict__ Wq_t,
    const float* __restrict__ Wout, unsigned short* __restrict__ Wo_t,
    const int* __restrict__ mask, unsigned long long* __restrict__ MP) {
  __shared__ float tile[32][33];
  const int bid = blockIdx.x, t = threadIdx.x;
  if (bid < 8192) {
    // cvt f32 -> bf16, 1024 elems/block
    int i = (bid * 256 + t) * 4;
    float4 v = *reinterpret_cast<const float4*>(x + i);
    ushort4 o;
    o.x = f2bf(v.x); o.y = f2bf(v.y); o.z = f2bf(v.z); o.w = f2bf(v.w);
    *reinterpret_cast<ushort4*>(Xb + i) = o;
  } else if (bid < 12288) {
    // transpose + convert 32x32 tile
    const float* in; unsigned short* out; int rows, cols, bx, by;
    if (bid < 11264) { int l = bid - 8192; in = Wqkv; out = Wq_t; rows = 1024; cols = 3072; bx = l % 96; by = l / 96; }
    else             { int l = bid - 11264; in = Wout; out = Wo_t; rows = 1024; cols = 1024; bx = l & 31; by = l >> 5; }
    int tx = t & 31, ty = t >> 5;  // 32 x 8
    int c0 = bx * 32, r0 = by * 32;
#pragma unroll
    for (int i = 0; i < 32; i += 8)
      tile[ty + i][tx] = in[(size_t)(r0 + ty + i) * cols + (c0 + tx)];
    __syncthreads();
#pragma unroll
    for (int i = 0; i < 32; i += 8)
      out[(size_t)(c0 + ty + i) * rows + (r0 + tx)] = f2bf(tile[tx][ty + i]);
  } else {
    // pack mask int32 [row][2048] -> bits uint64 [row][32] (bit k = masked)
    const int row = bid - 12288;             // b*2048 + n
    const int w = t >> 6, lane = t & 63;
    const int* mrow = mask + (size_t)row * 2048;
#pragma unroll
    for (int it = 0; it < 8; ++it) {
      int key = it * 256 + w * 64 + lane;
      unsigned long long bal = __ballot(mrow[key] == 1);
      if (lane == 0) MP[(size_t)row * 32 + it * 4 + w] = bal;
    }
  }
}

// ---------------- GEMM: C[8192][N] = A[8192][1024] @ Bt[N][1024]^T ----------------
// EPI==0: LDS-restaged coalesced epilogue into Q (pre-scaled) / K [bh][2048][64],
//         V^T [bh][64][2048]. grid (24,64).  EPI==1: f32 out + bias. grid (8,64).
// Default block order (R9 showed default round-robin beats chunked XCD swizzle here).
template <int EPI>
__global__ __launch_bounds__(256) void k_gemm(
    const unsigned short* __restrict__ A, const unsigned short* __restrict__ Bt,
    unsigned short* __restrict__ Qo, unsigned short* __restrict__ Ko,
    unsigned short* __restrict__ Vo, float* __restrict__ Co,
    const float* __restrict__ bias) {
  // k-loop: As = Smem[0:8192), Bs = Smem[8192:16384). epilogue: Cs = Smem, stride 132.
  __shared__ __align__(16) short Smem[16896];   // 33792 B
  short* As = Smem;
  short* Bs = Smem + 8192;
  const int t = threadIdx.x;
  const int bn = blockIdx.x, bm = blockIdx.y;
  const int wid = t >> 6, lane = t & 63, g = lane >> 4, l15 = lane & 15;
  const int wr = wid >> 1, wc = wid & 1;
  f32x4 zero = {0.f, 0.f, 0.f, 0.f};
  f32x4 acc[4][4];
#pragma unroll
  for (int i = 0; i < 4; ++i)
#pragma unroll
    for (int j = 0; j < 4; ++j) acc[i][j] = zero;

  const char* Ab = (const char*)(A + (size_t)bm * 128 * 1024);  // row stride 2048B
  const char* Bb = (const char*)(Bt + (size_t)bn * 128 * 1024);

  for (int k0 = 0; k0 < 2048; k0 += 128) {   // K-step: 64 elems = 128 bytes
#pragma unroll
    for (int q = 0; q < 4; ++q) {
      int idx = t + q * 256, r = idx >> 3, c = idx & 7;
      int sw = (c * 16) ^ ((r & 7) << 4);
      gload16(Ab + (size_t)r * 2048 + k0 + sw, (char*)As + idx * 16);
      gload16(Bb + (size_t)r * 2048 + k0 + sw, (char*)Bs + idx * 16);
    }
    asm volatile("s_waitcnt vmcnt(0)" ::: "memory");
    __syncthreads();
#pragma unroll
    for (int ks = 0; ks < 2; ++ks) {
      bf16x8 a[4], b[4];
#pragma unroll
      for (int mi = 0; mi < 4; ++mi) a[mi] = ldsw(As, wr * 64 + mi * 16 + l15, ks * 32 + g * 8);
#pragma unroll
      for (int ni = 0; ni < 4; ++ni) b[ni] = ldsw(Bs, wc * 64 + ni * 16 + l15, ks * 32 + g * 8);
#pragma unroll
      for (int mi = 0; mi < 4; ++mi)
#pragma unroll
        for (int ni = 0; ni < 4; ++ni)
          acc[mi][ni] = __builtin_amdgcn_mfma_f32_16x16x32_bf16(a[mi], b[ni], acc[mi][ni], 0, 0, 0);
    }
    __syncthreads();   // also guards Smem reuse by the epilogue
  }

  if (EPI == 1) {
#pragma unroll
    for (int mi = 0; mi < 4; ++mi)
#pragma unroll
      for (int ni = 0; ni < 4; ++ni)
#pragma unroll
        for (int j = 0; j < 4; ++j) {
          int row = bm * 128 + wr * 64 + mi * 16 + g * 4 + j;
          int col = bn * 128 + wc * 64 + ni * 16 + l15;
          Co[(size_t)row * 1024 + col] = acc[mi][ni][j] + bias[col];
        }
    return;
  }

  // ---- EPI==0 coalesced epilogue ----
  const int s = bn >> 3;                 // 0=Q,1=K,2=V (uniform per block)
  const int h0 = (bn & 7) * 2;           // two heads in this tile
  const int bglob = (bm * 128) >> 11;    // batch (tile never straddles batches)
  const int n0 = (bm * 128) & 2047;

  if (s < 2) {
    const float qs = (s == 0) ? 0.18033688011112042f : 1.0f;  // 0.125*log2(e) for Q
    // stage Cs[row][col], stride 132 shorts
#pragma unroll
    for (int mi = 0; mi < 4; ++mi)
#pragma unroll
      for (int ni = 0; ni < 4; ++ni)
#pragma unroll
        for (int j = 0; j < 4; ++j)
          Smem[(wr * 64 + mi * 16 + g * 4 + j) * 132 + wc * 64 + ni * 16 + l15] =
              (short)f2bf(acc[mi][ni][j] * qs);
    __syncthreads();
    // copy out: thread -> row r, head-half hh; 64 shorts = 128B contiguous dest
    int r = t >> 1, hh = t & 1;
    unsigned short* dst = (s == 0 ? Qo : Ko) +
        (((size_t)(bglob * 16 + h0 + hh)) * 2048 + n0 + r) * 64;
    const short* src = Smem + r * 132 + hh * 64;
#pragma unroll
    for (int k = 0; k < 8; ++k) {
      uint2 a = *reinterpret_cast<const uint2*>(src + k * 8);
      uint2 b2 = *reinterpret_cast<const uint2*>(src + k * 8 + 4);
      uint4 w = {a.x, a.y, b2.x, b2.y};
      *reinterpret_cast<uint4*>(dst + k * 8) = w;
    }
  } else {
    // V: stage TRANSPOSED Cs_t[col][row] stride 132; per-fragment 4 j-rows adjacent -> b64
#pragma unroll
    for (int mi = 0; mi < 4; ++mi)
#pragma unroll
      for (int ni = 0; ni < 4; ++ni) {
        unsigned x0 = f2bf(acc[mi][ni][0]), x1 = f2bf(acc[mi][ni][1]);
        unsigned x2 = f2bf(acc[mi][ni][2]), x3 = f2bf(acc[mi][ni][3]);
        uint2 pk = {x0 | (x1 << 16), x2 | (x3 << 16)};
        int col = wc * 64 + ni * 16 + l15;
        int row = wr * 64 + mi * 16 + g * 4;
        *reinterpret_cast<uint2*>(Smem + col * 132 + row) = pk;
      }
    __syncthreads();
    // copy out: thread -> col c (head h, dim d), row-half seg; 64 shorts contiguous dest
    int c = t >> 1, seg = t & 1;
    int h = h0 + (c >> 6), d = c & 63;
    unsigned short* dst = Vo + ((size_t)(bglob * 16 + h) * 64 + d) * 2048 + n0 + seg * 64;
    const short* src = Smem + c * 132 + seg * 64;
#pragma unroll
    for (int k = 0; k < 8; ++k) {
      uint2 a = *reinterpret_cast<const uint2*>(src + k * 8);
      uint2 b2 = *reinterpret_cast<const uint2*>(src + k * 8 + 4);
      uint4 w = {a.x, a.y, b2.x, b2.y};
      *reinterpret_cast<uint4*>(dst + k * 8) = w;
    }
  }
}

// One attention KV-tile. CBUF is a compile-time constant -> all LDS read/write
// addresses are loop-invariant per-lane values + immediate offsets.
#define ATTN_TILE(CBUF, KT, IS_LAST)                                          \
  {                                                                           \
    unsigned long long mw = mrow[(KT)];                                       \
    gload16(Vb + (size_t)(KT) * 128 + vboff, (char*)&Vt[0] + t * 16);         \
    if (!(IS_LAST))                                                           \
      gload16(Kb + (size_t)((KT) + 1) * 8192 + kboff,                         \
              (char*)&Ks[(CBUF) ^ 1][0] + t * 16);                            \
    unsigned mlo = (unsigned)mw >> (g * 4);                                   \
    unsigned mhi = (unsigned)(mw >> 32) >> (g * 4);                           \
    _Pragma("unroll")                                                         \
    for (int kh = 0; kh < 2; ++kh) {                                          \
      f32x4 sf[2] = {zero, zero};                                             \
      __builtin_amdgcn_s_setprio(1);                                          \
      _Pragma("unroll")                                                       \
      for (int ds = 0; ds < 2; ++ds) {                                        \
        bf16x8 qk = ds ? qf1 : qf0;                                           \
        _Pragma("unroll")                                                     \
        for (int nf2 = 0; nf2 < 2; ++nf2) {                                   \
          bf16x8 kk = ldsw(&Ks[(CBUF)][0], (kh * 2 + nf2) * 16 + l15,         \
                           ds * 32 + g * 8);                                  \
          sf[nf2] =                                                           \
              __builtin_amdgcn_mfma_f32_16x16x32_bf16(kk, qk, sf[nf2], 0, 0, 0); \
        }                                                                     \
      }                                                                       \
      __builtin_amdgcn_s_setprio(0);                                         \
      unsigned msrc = kh ? mhi : mlo;                                         \
      _Pragma("unroll")                                                       \
      for (int nf2 = 0; nf2 < 2; ++nf2) {                                     \
        unsigned eu[4];                                                       \
        _Pragma("unroll")                                                     \
        for (int j = 0; j < 4; ++j) {                                         \
          float s = sf[nf2][j];                                               \
          if (msrc & (1u << (nf2 * 16 + j))) s = -1e30f;                      \
          float e = __builtin_amdgcn_exp2f(s);                                \
          lp += e;                                                            \
          eu[j] = __builtin_bit_cast(unsigned, e);                            \
        }                                                                     \
        uint2 pk;                                                             \
        pk.x = __builtin_amdgcn_perm(eu[1], eu[0], 0x07060302);               \
        pk.y = __builtin_amdgcn_perm(eu[3], eu[2], 0x07060302);               \
        *reinterpret_cast<uint2*>(PwB + (nf2 ? (ps_wr0 ^ 32) : ps_wr0)) = pk; \
      }                                                                       \
      if (kh == 0) {                                                          \
        if (!(IS_LAST))                                                       \
          asm volatile("s_waitcnt vmcnt(1) lgkmcnt(0)" ::: "memory");         \
        else                                                                  \
          asm volatile("s_waitcnt vmcnt(0) lgkmcnt(0)" ::: "memory");         \
        __builtin_amdgcn_s_barrier();                                         \
        __builtin_amdgcn_sched_barrier(0);                                    \
      } else {                                                                \
        asm volatile("s_waitcnt lgkmcnt(0)" ::: "memory");                    \
        __builtin_amdgcn_sched_barrier(0);                                    \
      }                                                                       \
      bf16x8 ap = *reinterpret_cast<const bf16x8*>(PwB + ps_rd);              \
      __builtin_amdgcn_s_setprio(1);                                          \
      _Pragma("unroll")                                                       \
      for (int nf = 0; nf < 4; ++nf) {                                        \
        bf16x8 bv = ldsw(&Vt[0], nf * 16 + l15, kh * 32 + g * 8);             \
        oacc[nf] =                                                            \
            __builtin_amdgcn_mfma_f32_16x16x32_bf16(ap, bv, oacc[nf], 0, 0, 0); \
      }                                                                       \
      __builtin_amdgcn_s_setprio(0);                                         \
    }                                                                         \
    asm volatile("s_waitcnt vmcnt(0)" ::: "memory");                          \
    __builtin_amdgcn_s_barrier();                                            \
  }

// ---------------- flash attention ----------------
// grid 1024 (XCD-swizzled), 512 threads = 8 waves; QBLK=128, KV tile 64.
// Swapped QK^T: S^T = mfma(K, Q) -> lane (g,l15) holds 16 keys for q=l15.
// Key-half pipeline: {QK(2 frags) -> softmax -> pack -> PV} per 32-key half.
// K double-buffered; V single-buffered (mid-tile counted vmcnt + raw s_barrier).
// kt unrolled x2 via macro: static Ks buffer per sub-body -> LDS addresses become
// loop-invariant + immediates (runtime-cb recomputed them every iteration).
// Outer loop stays rolled x16 (full unroll = R6 live-range explosion).
__global__ __launch_bounds__(512, 6) void k_attn(
    const unsigned short* __restrict__ Q, const unsigned short* __restrict__ K,
    const unsigned short* __restrict__ Vt_g, const unsigned long long* __restrict__ pack,
    unsigned short* __restrict__ O) {
  __shared__ __align__(16) short Ks[2][64 * 64];    // 16KB
  __shared__ __align__(16) short Vt[64 * 64];       // 8KB  [d][key], single buffer
  __shared__ __align__(16) short Ps[8][16 * 32];    // 8KB per-wave P half [q][32key], swz
  const int bid0 = blockIdx.x;
  const int bid = (bid0 & 7) * 128 + (bid0 >> 3);   // XCD chunked swizzle (1024%8==0)
  const int qt = bid & 15, bh = bid >> 4;           // 16 q-tiles of 128
  const int b = bh >> 4;
  const int t = threadIdx.x, wid = t >> 6, lane = t & 63, g = lane >> 4, l15 = lane & 15;
  const char* Kb = (const char*)(K + (size_t)bh * (2048 * 64));     // row 128B
  const char* Vb = (const char*)(Vt_g + (size_t)bh * (64 * 2048));  // row 4096B
  const unsigned short* Qb = Q + (size_t)bh * (2048 * 64);

  // per-lane loop-invariant offsets
  const int sr = t >> 3, sc = t & 7;
  const int sw_src = (sc * 16) ^ ((sr & 7) << 4);
  const int kboff = sr * 128 + sw_src;              // K within-tile byte offset
  const int vboff = sr * 4096 + sw_src;             // V fixed-row byte offset
  char* PwB = (char*)&Ps[wid][0];                   // 16 rows x 64B
  const int ps_rd  = (l15 * 64 + g * 16) ^ ((l15 & 7) << 4);  // b128 read
  const int ps_wr0 = (l15 * 64 + g * 8) ^ ((l15 & 7) << 4);   // b64 write nf2=0
  // nf2=1 write offset == ps_wr0 ^ 32 (bit 5 untouched by +g*8, l15*64)

  // prologue: stage K tile 0 only (V(0) staged inside tile 0)
  gload16(Kb + kboff, (char*)&Ks[0][0] + t * 16);
  // Q fragments to registers (B-operand of swapped QK^T): q = l15 row of wave's block
  const int qrow = qt * 128 + wid * 16 + l15;
  bf16x8 qf0 = *reinterpret_cast<const bf16x8*>(Qb + (size_t)qrow * 64 + g * 8);
  bf16x8 qf1 = *reinterpret_cast<const bf16x8*>(Qb + (size_t)qrow * 64 + 32 + g * 8);
  const unsigned long long* mrow = pack + ((size_t)b * 2048 + qrow) * 32;
  asm volatile("s_waitcnt vmcnt(0)" ::: "memory");
  __syncthreads();

  f32x4 zero = {0.f, 0.f, 0.f, 0.f};
  f32x4 oacc[4];
#pragma unroll
  for (int nf = 0; nf < 4; ++nf) oacc[nf] = zero;
  float lp = 0.f;                                   // partial row-sum for q=l15

#pragma unroll 1
  for (int it = 0; it < 16; ++it) {
    const int kt0 = it * 2;
    ATTN_TILE(0, kt0, 0)
    ATTN_TILE(1, kt0 + 1, it == 15)
  }

  // total row-sum for q=l15 (4 lanes per q across g-groups), redistribute inverse
  float l = lp;
  l += __shfl_xor(l, 16);
  l += __shfl_xor(l, 32);
  float invl = 1.0f / l;
  float inv[4];
#pragma unroll
  for (int j = 0; j < 4; ++j) inv[j] = __shfl(invl, g * 4 + j);  // lane l15==g*4+j

  // write attention output: ATT[b][n][h*64+d] bf16 ; O-tile: q=g*4+j, d=nf*16+l15
  const int h = bh & 15;
#pragma unroll
  for (int nf = 0; nf < 4; ++nf) {
#pragma unroll
    for (int j = 0; j < 4; ++j) {
      int qg = qt * 128 + wid * 16 + g * 4 + j;
      int d = nf * 16 + l15;
      O[((size_t)b * 2048 + qg) * 1024 + h * 64 + d] = f2bf(oacc[nf][j] * inv[j]);
    }
  }
}

extern "C" void kernel_launch(void* const* d_in, const int* in_sizes, int n_in,
                              void* d_out, int out_size, void* d_ws, size_t ws_size,
                              hipStream_t stream) {
  (void)in_sizes; (void)n_in; (void)out_size; (void)ws_size;
  const float* x = (const float*)d_in[0];
  const int* mask = (const int*)d_in[1];
  const float* Wqkv = (const float*)d_in[2];
  const float* Wout = (const float*)d_in[3];
  const float* bout = (const float*)d_in[4];
  float* out = (float*)d_out;

  unsigned short* ws = (unsigned short*)d_ws;
  unsigned short* Xb   = ws;                  // 8,388,608 elems
  unsigned short* Wq_t = Xb + 8388608;        // 3,145,728
  unsigned short* Wo_t = Wq_t + 3145728;      // 1,048,576
  unsigned short* Qa   = Wo_t + 1048576;      // 8,388,608 (pre-scaled by 0.125*log2e)
  unsigned short* Ka   = Qa + 8388608;        // 8,388,608
  unsigned short* Va   = Ka + 8388608;        // 8,388,608 (transposed [bh][64][2048])
  unsigned short* ATT  = Va + 8388608;        // 8,388,608
  unsigned long long* MP = (unsigned long long*)(ATT + 8388608);  // 2 MB

  k_prep<<<20480, 256, 0, stream>>>(x, Xb, Wqkv, Wq_t, Wout, Wo_t, mask, MP);
  k_gemm<0><<<dim3(24, 64), 256, 0, stream>>>(Xb, Wq_t, Qa, Ka, Va, nullptr, nullptr);
  k_attn<<<1024, 512, 0, stream>>>(Qa, Ka, Va, MP, ATT);
  k_gemm<1><<<dim3(8, 64), 256, 0, stream>>>(ATT, Wo_t, nullptr, nullptr, nullptr, out, bout);
}

// Round 14
// 241.089 us; speedup vs baseline: 1.0318x; 1.0318x over previous
//
#include <hip/hip_runtime.h>
#include <hip/hip_bf16.h>

// SelfAttentionMasked: B=4, N=2048, DIM=1024, H=16, DH=64
// k_prep (cvt(x) + transpose_cvt(Wqkv,Wout) + packmask, one dispatch)
// -> QKV GEMM (gload_lds+swizzle, LDS-restaged coalesced epilogue, Q pre-scaled by
// 0.125*log2e) -> flash attn (16x16 swapped QK^T, key-half pipeline, single-buffered
// V + counted mid-tile join, post-exp keep-mask, 4-way lp accumulators) -> out GEMM

typedef __attribute__((ext_vector_type(8))) short bf16x8;
typedef __attribute__((ext_vector_type(4))) float f32x4;

__device__ __forceinline__ unsigned short f2bf(float f) {
  unsigned u = __builtin_bit_cast(unsigned, f);
  u += 0x7fffu + ((u >> 16) & 1u);   // RNE
  return (unsigned short)(u >> 16);
}

// async global->LDS, 16B per lane; LDS dest linear (wave-uniform base + lane*16)
__device__ __forceinline__ void gload16(const void* g, void* l) {
  __builtin_amdgcn_global_load_lds(
      (const __attribute__((address_space(1))) unsigned int*)g,
      (__attribute__((address_space(3))) unsigned int*)l, 16, 0, 0);
}

// swizzled b128 read from a [rows][64-elem] linear LDS tile staged with
// source-byte ^= ((row&7)<<4). elem must be a multiple of 8.
__device__ __forceinline__ bf16x8 ldsw(const short* base, int row, int elem) {
  const char* p = (const char*)base + row * 128 + ((elem * 2) ^ ((row & 7) << 4));
  return *(const bf16x8*)p;
}

// ---------------- fused prep: cvt(x) | transpose_cvt(Wqkv) | transpose_cvt(Wout)
// ---------------- | packmask.  All independent; branch on blockIdx range.
__global__ __launch_bounds__(256) void k_prep(
    const float* __restrict__ x, unsigned short* __restrict__ Xb,
    const float* __restrict__ Wqkv, unsigned short* __restrict__ Wq_t,
    const float* __restrict__ Wout, unsigned short* __restrict__ Wo_t,
    const int* __restrict__ mask, unsigned long long* __restrict__ MP) {
  __shared__ float tile[32][33];
  const int bid = blockIdx.x, t = threadIdx.x;
  if (bid < 8192) {
    // cvt f32 -> bf16, 1024 elems/block
    int i = (bid * 256 + t) * 4;
    float4 v = *reinterpret_cast<const float4*>(x + i);
    ushort4 o;
    o.x = f2bf(v.x); o.y = f2bf(v.y); o.z = f2bf(v.z); o.w = f2bf(v.w);
    *reinterpret_cast<ushort4*>(Xb + i) = o;
  } else if (bid < 12288) {
    // transpose + convert 32x32 tile
    const float* in; unsigned short* out; int rows, cols, bx, by;
    if (bid < 11264) { int l = bid - 8192; in = Wqkv; out = Wq_t; rows = 1024; cols = 3072; bx = l % 96; by = l / 96; }
    else             { int l = bid - 11264; in = Wout; out = Wo_t; rows = 1024; cols = 1024; bx = l & 31; by = l >> 5; }
    int tx = t & 31, ty = t >> 5;  // 32 x 8
    int c0 = bx * 32, r0 = by * 32;
#pragma unroll
    for (int i = 0; i < 32; i += 8)
      tile[ty + i][tx] = in[(size_t)(r0 + ty + i) * cols + (c0 + tx)];
    __syncthreads();
#pragma unroll
    for (int i = 0; i < 32; i += 8)
      out[(size_t)(c0 + ty + i) * rows + (r0 + tx)] = f2bf(tile[tx][ty + i]);
  } else {
    // pack mask int32 [row][2048] -> bits uint64 [row][32] (bit k = masked)
    const int row = bid - 12288;             // b*2048 + n
    const int w = t >> 6, lane = t & 63;
    const int* mrow = mask + (size_t)row * 2048;
#pragma unroll
    for (int it = 0; it < 8; ++it) {
      int key = it * 256 + w * 64 + lane;
      unsigned long long bal = __ballot(mrow[key] == 1);
      if (lane == 0) MP[(size_t)row * 32 + it * 4 + w] = bal;
    }
  }
}

// ---------------- GEMM: C[8192][N] = A[8192][1024] @ Bt[N][1024]^T ----------------
// EPI==0: LDS-restaged coalesced epilogue into Q (pre-scaled) / K [bh][2048][64],
//         V^T [bh][64][2048]. grid (24,64).  EPI==1: f32 out + bias. grid (8,64).
// Default block order (R9 showed default round-robin beats chunked XCD swizzle here).
template <int EPI>
__global__ __launch_bounds__(256) void k_gemm(
    const unsigned short* __restrict__ A, const unsigned short* __restrict__ Bt,
    unsigned short* __restrict__ Qo, unsigned short* __restrict__ Ko,
    unsigned short* __restrict__ Vo, float* __restrict__ Co,
    const float* __restrict__ bias) {
  // k-loop: As = Smem[0:8192), Bs = Smem[8192:16384). epilogue: Cs = Smem, stride 132.
  __shared__ __align__(16) short Smem[16896];   // 33792 B
  short* As = Smem;
  short* Bs = Smem + 8192;
  const int t = threadIdx.x;
  const int bn = blockIdx.x, bm = blockIdx.y;
  const int wid = t >> 6, lane = t & 63, g = lane >> 4, l15 = lane & 15;
  const int wr = wid >> 1, wc = wid & 1;
  f32x4 zero = {0.f, 0.f, 0.f, 0.f};
  f32x4 acc[4][4];
#pragma unroll
  for (int i = 0; i < 4; ++i)
#pragma unroll
    for (int j = 0; j < 4; ++j) acc[i][j] = zero;

  const char* Ab = (const char*)(A + (size_t)bm * 128 * 1024);  // row stride 2048B
  const char* Bb = (const char*)(Bt + (size_t)bn * 128 * 1024);

  for (int k0 = 0; k0 < 2048; k0 += 128) {   // K-step: 64 elems = 128 bytes
#pragma unroll
    for (int q = 0; q < 4; ++q) {
      int idx = t + q * 256, r = idx >> 3, c = idx & 7;
      int sw = (c * 16) ^ ((r & 7) << 4);
      gload16(Ab + (size_t)r * 2048 + k0 + sw, (char*)As + idx * 16);
      gload16(Bb + (size_t)r * 2048 + k0 + sw, (char*)Bs + idx * 16);
    }
    asm volatile("s_waitcnt vmcnt(0)" ::: "memory");
    __syncthreads();
#pragma unroll
    for (int ks = 0; ks < 2; ++ks) {
      bf16x8 a[4], b[4];
#pragma unroll
      for (int mi = 0; mi < 4; ++mi) a[mi] = ldsw(As, wr * 64 + mi * 16 + l15, ks * 32 + g * 8);
#pragma unroll
      for (int ni = 0; ni < 4; ++ni) b[ni] = ldsw(Bs, wc * 64 + ni * 16 + l15, ks * 32 + g * 8);
#pragma unroll
      for (int mi = 0; mi < 4; ++mi)
#pragma unroll
        for (int ni = 0; ni < 4; ++ni)
          acc[mi][ni] = __builtin_amdgcn_mfma_f32_16x16x32_bf16(a[mi], b[ni], acc[mi][ni], 0, 0, 0);
    }
    __syncthreads();   // also guards Smem reuse by the epilogue
  }

  if (EPI == 1) {
#pragma unroll
    for (int mi = 0; mi < 4; ++mi)
#pragma unroll
      for (int ni = 0; ni < 4; ++ni)
#pragma unroll
        for (int j = 0; j < 4; ++j) {
          int row = bm * 128 + wr * 64 + mi * 16 + g * 4 + j;
          int col = bn * 128 + wc * 64 + ni * 16 + l15;
          Co[(size_t)row * 1024 + col] = acc[mi][ni][j] + bias[col];
        }
    return;
  }

  // ---- EPI==0 coalesced epilogue ----
  const int s = bn >> 3;                 // 0=Q,1=K,2=V (uniform per block)
  const int h0 = (bn & 7) * 2;           // two heads in this tile
  const int bglob = (bm * 128) >> 11;    // batch (tile never straddles batches)
  const int n0 = (bm * 128) & 2047;

  if (s < 2) {
    const float qs = (s == 0) ? 0.18033688011112042f : 1.0f;  // 0.125*log2(e) for Q
    // stage Cs[row][col], stride 132 shorts
#pragma unroll
    for (int mi = 0; mi < 4; ++mi)
#pragma unroll
      for (int ni = 0; ni < 4; ++ni)
#pragma unroll
        for (int j = 0; j < 4; ++j)
          Smem[(wr * 64 + mi * 16 + g * 4 + j) * 132 + wc * 64 + ni * 16 + l15] =
              (short)f2bf(acc[mi][ni][j] * qs);
    __syncthreads();
    // copy out: thread -> row r, head-half hh; 64 shorts = 128B contiguous dest
    int r = t >> 1, hh = t & 1;
    unsigned short* dst = (s == 0 ? Qo : Ko) +
        (((size_t)(bglob * 16 + h0 + hh)) * 2048 + n0 + r) * 64;
    const short* src = Smem + r * 132 + hh * 64;
#pragma unroll
    for (int k = 0; k < 8; ++k) {
      uint2 a = *reinterpret_cast<const uint2*>(src + k * 8);
      uint2 b2 = *reinterpret_cast<const uint2*>(src + k * 8 + 4);
      uint4 w = {a.x, a.y, b2.x, b2.y};
      *reinterpret_cast<uint4*>(dst + k * 8) = w;
    }
  } else {
    // V: stage TRANSPOSED Cs_t[col][row] stride 132; per-fragment 4 j-rows adjacent -> b64
#pragma unroll
    for (int mi = 0; mi < 4; ++mi)
#pragma unroll
      for (int ni = 0; ni < 4; ++ni) {
        unsigned x0 = f2bf(acc[mi][ni][0]), x1 = f2bf(acc[mi][ni][1]);
        unsigned x2 = f2bf(acc[mi][ni][2]), x3 = f2bf(acc[mi][ni][3]);
        uint2 pk = {x0 | (x1 << 16), x2 | (x3 << 16)};
        int col = wc * 64 + ni * 16 + l15;
        int row = wr * 64 + mi * 16 + g * 4;
        *reinterpret_cast<uint2*>(Smem + col * 132 + row) = pk;
      }
    __syncthreads();
    // copy out: thread -> col c (head h, dim d), row-half seg; 64 shorts contiguous dest
    int c = t >> 1, seg = t & 1;
    int h = h0 + (c >> 6), d = c & 63;
    unsigned short* dst = Vo + ((size_t)(bglob * 16 + h) * 64 + d) * 2048 + n0 + seg * 64;
    const short* src = Smem + c * 132 + seg * 64;
#pragma unroll
    for (int k = 0; k < 8; ++k) {
      uint2 a = *reinterpret_cast<const uint2*>(src + k * 8);
      uint2 b2 = *reinterpret_cast<const uint2*>(src + k * 8 + 4);
      uint4 w = {a.x, a.y, b2.x, b2.y};
      *reinterpret_cast<uint4*>(dst + k * 8) = w;
    }
  }
}

// ---------------- flash attention ----------------
// grid 1024 (XCD-swizzled), 512 threads = 8 waves; QBLK=128, KV tile 64.
// Swapped QK^T: S^T = mfma(K, Q) -> lane (g,l15) holds 16 keys for q=l15.
// Key-half pipeline: {QK(2 frags) -> softmax -> pack -> PV} per 32-key half.
// K double-buffered; V SINGLE-buffered (counted mid-tile vmcnt + raw s_barrier).
// LDS = 32768B -> 4 blocks/CU. Loop ROLLED, runtime cb (R12-proven codegen; 2x
// macro-unroll regressed to 120us in R13 -- do not unroll).
// This round: (1) post-exp keep-mask (bfe+and on exp RESULT, off the pre-exp
// chain; bit-identical); (2) 4-way lp accumulators (serial 16-add fp chain -> 4).
__global__ __launch_bounds__(512, 8) void k_attn(
    const unsigned short* __restrict__ Q, const unsigned short* __restrict__ K,
    const unsigned short* __restrict__ Vt_g, const unsigned long long* __restrict__ pack,
    unsigned short* __restrict__ O) {
  __shared__ __align__(16) short Ks[2][64 * 64];    // 16KB
  __shared__ __align__(16) short Vt[64 * 64];       // 8KB  [d][key], single buffer
  __shared__ __align__(16) short Ps[8][16 * 32];    // 8KB per-wave P half [q][32key], swz
  const int bid0 = blockIdx.x;
  const int bid = (bid0 & 7) * 128 + (bid0 >> 3);   // XCD chunked swizzle (1024%8==0)
  const int qt = bid & 15, bh = bid >> 4;           // 16 q-tiles of 128
  const int b = bh >> 4;
  const int t = threadIdx.x, wid = t >> 6, lane = t & 63, g = lane >> 4, l15 = lane & 15;
  const char* Kb = (const char*)(K + (size_t)bh * (2048 * 64));     // row 128B
  const char* Vb = (const char*)(Vt_g + (size_t)bh * (64 * 2048));  // row 4096B
  const unsigned short* Qb = Q + (size_t)bh * (2048 * 64);

  // per-lane loop-invariant offsets
  const int sr = t >> 3, sc = t & 7;
  const int sw_src = (sc * 16) ^ ((sr & 7) << 4);
  char* PwB = (char*)&Ps[wid][0];                   // 16 rows x 64B
  const int ps_rd  = (l15 * 64 + g * 16) ^ ((l15 & 7) << 4);  // b128 read
  const int ps_wr0 = (l15 * 64 + g * 8) ^ ((l15 & 7) << 4);   // b64 write nf2=0
  // nf2=1 write offset == ps_wr0 ^ 32 (bit 5 untouched by +g*8, l15*64)

  // prologue: stage K tile 0 only (V(0) staged inside tile 0)
  gload16(Kb + (size_t)sr * 128 + sw_src, (char*)&Ks[0][0] + t * 16);
  // Q fragments to registers (B-operand of swapped QK^T): q = l15 row of wave's block
  const int qrow = qt * 128 + wid * 16 + l15;
  bf16x8 qf0 = *reinterpret_cast<const bf16x8*>(Qb + (size_t)qrow * 64 + g * 8);
  bf16x8 qf1 = *reinterpret_cast<const bf16x8*>(Qb + (size_t)qrow * 64 + 32 + g * 8);
  const unsigned long long* mrow = pack + ((size_t)b * 2048 + qrow) * 32;
  asm volatile("s_waitcnt vmcnt(0)" ::: "memory");
  __syncthreads();

  f32x4 zero = {0.f, 0.f, 0.f, 0.f};
  f32x4 oacc[4];
#pragma unroll
  for (int nf = 0; nf < 4; ++nf) oacc[nf] = zero;
  float lpj0 = 0.f, lpj1 = 0.f, lpj2 = 0.f, lpj3 = 0.f;  // 4-way row-sum partials

  int cb = 0;
#pragma unroll 1
  for (int kt = 0; kt < 32; ++kt) {
    const int nb = cb ^ 1;
    // issue order matters for counted vmcnt: mask (oldest), V(t), K(t+1) (newest)
    unsigned long long mw = mrow[kt];
    gload16(Vb + (size_t)sr * 4096 + kt * 128 + sw_src, (char*)&Vt[0] + t * 16);
    if (kt + 1 < 32)
      gload16(Kb + (size_t)((kt + 1) * 64 + sr) * 128 + sw_src, (char*)&Ks[nb][0] + t * 16);
    // keep-masks (inverted): bit set = KEEP the score
    unsigned klo = ~((unsigned)mw >> (g * 4));      // key nf*16+g*4+j -> bit nf*16+j
    unsigned khi = ~((unsigned)(mw >> 32) >> (g * 4));
#pragma unroll
    for (int kh = 0; kh < 2; ++kh) {                // 32-key half pipeline
      f32x4 sf[2] = {zero, zero};
      __builtin_amdgcn_s_setprio(1);
#pragma unroll
      for (int ds = 0; ds < 2; ++ds) {              // d-halves (contraction)
        bf16x8 qk = ds ? qf1 : qf0;
#pragma unroll
        for (int nf2 = 0; nf2 < 2; ++nf2) {
          bf16x8 kk = ldsw(&Ks[cb][0], (kh * 2 + nf2) * 16 + l15, ds * 32 + g * 8);
          sf[nf2] = __builtin_amdgcn_mfma_f32_16x16x32_bf16(kk, qk, sf[nf2], 0, 0, 0);
        }
      }
      __builtin_amdgcn_s_setprio(0);
      // softmax half: exp2 (scores pre-scaled by 0.125*log2e), post-exp keep-mask,
      // 4-way partial sums, trunc-bf16 pack
      unsigned ksrc = kh ? khi : klo;
#pragma unroll
      for (int nf2 = 0; nf2 < 2; ++nf2) {
        unsigned eu[4];
#pragma unroll
        for (int j = 0; j < 4; ++j) {
          float e = __builtin_amdgcn_exp2f(sf[nf2][j]);
          // keep = 0xFFFFFFFF if keep-bit set, else 0 (sign-extend of bit)
          int keep = ((int)(ksrc << (31 - (nf2 * 16 + j)))) >> 31;
          eu[j] = __builtin_bit_cast(unsigned, e) & (unsigned)keep;
          float em = __builtin_bit_cast(float, eu[j]);
          if (j == 0) lpj0 += em;
          else if (j == 1) lpj1 += em;
          else if (j == 2) lpj2 += em;
          else lpj3 += em;
        }
        uint2 pk;                                    // trunc-bf16 pack (P>=0)
        pk.x = __builtin_amdgcn_perm(eu[1], eu[0], 0x07060302);
        pk.y = __builtin_amdgcn_perm(eu[3], eu[2], 0x07060302);
        *reinterpret_cast<uint2*>(PwB + (nf2 ? (ps_wr0 ^ 32) : ps_wr0)) = pk;
      }
      if (kh == 0) {
        // mid-tile join: V(t) staged for all waves (K(t+1) stays in flight), Ps drained
        if (kt + 1 < 32) asm volatile("s_waitcnt vmcnt(1) lgkmcnt(0)" ::: "memory");
        else             asm volatile("s_waitcnt vmcnt(0) lgkmcnt(0)" ::: "memory");
        __builtin_amdgcn_s_barrier();
        __builtin_amdgcn_sched_barrier(0);
      } else {
        // within-wave Ps write->read ordering only
        asm volatile("s_waitcnt lgkmcnt(0)" ::: "memory");
        __builtin_amdgcn_sched_barrier(0);
      }
      // PV half: A = P[q][32 keys], B = Vt rows (d), k-dim = this key half
      bf16x8 ap = *reinterpret_cast<const bf16x8*>(PwB + ps_rd);
      __builtin_amdgcn_s_setprio(1);
#pragma unroll
      for (int nf = 0; nf < 4; ++nf) {
        bf16x8 bv = ldsw(&Vt[0], nf * 16 + l15, kh * 32 + g * 8);
        oacc[nf] = __builtin_amdgcn_mfma_f32_16x16x32_bf16(ap, bv, oacc[nf], 0, 0, 0);
      }
      __builtin_amdgcn_s_setprio(0);
    }
    // end-of-tile: K(t+1) staged (only outstanding load); also fences Vt reuse
    asm volatile("s_waitcnt vmcnt(0)" ::: "memory");
    __builtin_amdgcn_s_barrier();
    cb = nb;
  }

  // total row-sum for q=l15 (4 lanes per q across g-groups), redistribute inverse
  float l = (lpj0 + lpj1) + (lpj2 + lpj3);
  l += __shfl_xor(l, 16);
  l += __shfl_xor(l, 32);
  float invl = 1.0f / l;
  float inv[4];
#pragma unroll
  for (int j = 0; j < 4; ++j) inv[j] = __shfl(invl, g * 4 + j);  // lane l15==g*4+j

  // write attention output: ATT[b][n][h*64+d] bf16 ; O-tile: q=g*4+j, d=nf*16+l15
  const int h = bh & 15;
#pragma unroll
  for (int nf = 0; nf < 4; ++nf) {
#pragma unroll
    for (int j = 0; j < 4; ++j) {
      int qg = qt * 128 + wid * 16 + g * 4 + j;
      int d = nf * 16 + l15;
      O[((size_t)b * 2048 + qg) * 1024 + h * 64 + d] = f2bf(oacc[nf][j] * inv[j]);
    }
  }
}

extern "C" void kernel_launch(void* const* d_in, const int* in_sizes, int n_in,
                              void* d_out, int out_size, void* d_ws, size_t ws_size,
                              hipStream_t stream) {
  (void)in_sizes; (void)n_in; (void)out_size; (void)ws_size;
  const float* x = (const float*)d_in[0];
  const int* mask = (const int*)d_in[1];
  const float* Wqkv = (const float*)d_in[2];
  const float* Wout = (const float*)d_in[3];
  const float* bout = (const float*)d_in[4];
  float* out = (float*)d_out;

  unsigned short* ws = (unsigned short*)d_ws;
  unsigned short* Xb   = ws;                  // 8,388,608 elems
  unsigned short* Wq_t = Xb + 8388608;        // 3,145,728
  unsigned short* Wo_t = Wq_t + 3145728;      // 1,048,576
  unsigned short* Qa   = Wo_t + 1048576;      // 8,388,608 (pre-scaled by 0.125*log2e)
  unsigned short* Ka   = Qa + 8388608;        // 8,388,608
  unsigned short* Va   = Ka + 8388608;        // 8,388,608 (transposed [bh][64][2048])
  unsigned short* ATT  = Va + 8388608;        // 8,388,608
  unsigned long long* MP = (unsigned long long*)(ATT + 8388608);  // 2 MB

  k_prep<<<20480, 256, 0, stream>>>(x, Xb, Wqkv, Wq_t, Wout, Wo_t, mask, MP);
  k_gemm<0><<<dim3(24, 64), 256, 0, stream>>>(Xb, Wq_t, Qa, Ka, Va, nullptr, nullptr);
  k_attn<<<1024, 512, 0, stream>>>(Qa, Ka, Va, MP, ATT);
  k_gemm<1><<<dim3(8, 64), 256, 0, stream>>>(ATT, Wo_t, nullptr, nullptr, nullptr, out, bout);
}

// Round 15
// 238.186 us; speedup vs baseline: 1.0444x; 1.0122x over previous
//
#include <hip/hip_runtime.h>
#include <hip/hip_bf16.h>

// SelfAttentionMasked: B=4, N=2048, DIM=1024, H=16, DH=64
// k_prep (cvt(x) + transpose_cvt(Wqkv,Wout) + packmask, one dispatch)
// -> QKV GEMM (gload_lds+swizzle, LDS-restaged coalesced epilogue, Q pre-scaled by
// 0.125*log2e) -> flash attn (16x16 swapped QK^T, key-half pipeline, single-buffered
// V + counted mid-tile join, 32KB LDS -> 4 blocks/CU) -> out GEMM + bias
// [R15 = exact revert to R12, the session's best-measured configuration]

typedef __attribute__((ext_vector_type(8))) short bf16x8;
typedef __attribute__((ext_vector_type(4))) float f32x4;

__device__ __forceinline__ unsigned short f2bf(float f) {
  unsigned u = __builtin_bit_cast(unsigned, f);
  u += 0x7fffu + ((u >> 16) & 1u);   // RNE
  return (unsigned short)(u >> 16);
}

// async global->LDS, 16B per lane; LDS dest linear (wave-uniform base + lane*16)
__device__ __forceinline__ void gload16(const void* g, void* l) {
  __builtin_amdgcn_global_load_lds(
      (const __attribute__((address_space(1))) unsigned int*)g,
      (__attribute__((address_space(3))) unsigned int*)l, 16, 0, 0);
}

// swizzled b128 read from a [rows][64-elem] linear LDS tile staged with
// source-byte ^= ((row&7)<<4). elem must be a multiple of 8.
__device__ __forceinline__ bf16x8 ldsw(const short* base, int row, int elem) {
  const char* p = (const char*)base + row * 128 + ((elem * 2) ^ ((row & 7) << 4));
  return *(const bf16x8*)p;
}

// ---------------- fused prep: cvt(x) | transpose_cvt(Wqkv) | transpose_cvt(Wout)
// ---------------- | packmask.  All independent; branch on blockIdx range.
__global__ __launch_bounds__(256) void k_prep(
    const float* __restrict__ x, unsigned short* __restrict__ Xb,
    const float* __restrict__ Wqkv, unsigned short* __restrict__ Wq_t,
    const float* __restrict__ Wout, unsigned short* __restrict__ Wo_t,
    const int* __restrict__ mask, unsigned long long* __restrict__ MP) {
  __shared__ float tile[32][33];
  const int bid = blockIdx.x, t = threadIdx.x;
  if (bid < 8192) {
    // cvt f32 -> bf16, 1024 elems/block
    int i = (bid * 256 + t) * 4;
    float4 v = *reinterpret_cast<const float4*>(x + i);
    ushort4 o;
    o.x = f2bf(v.x); o.y = f2bf(v.y); o.z = f2bf(v.z); o.w = f2bf(v.w);
    *reinterpret_cast<ushort4*>(Xb + i) = o;
  } else if (bid < 12288) {
    // transpose + convert 32x32 tile
    const float* in; unsigned short* out; int rows, cols, bx, by;
    if (bid < 11264) { int l = bid - 8192; in = Wqkv; out = Wq_t; rows = 1024; cols = 3072; bx = l % 96; by = l / 96; }
    else             { int l = bid - 11264; in = Wout; out = Wo_t; rows = 1024; cols = 1024; bx = l & 31; by = l >> 5; }
    int tx = t & 31, ty = t >> 5;  // 32 x 8
    int c0 = bx * 32, r0 = by * 32;
#pragma unroll
    for (int i = 0; i < 32; i += 8)
      tile[ty + i][tx] = in[(size_t)(r0 + ty + i) * cols + (c0 + tx)];
    __syncthreads();
#pragma unroll
    for (int i = 0; i < 32; i += 8)
      out[(size_t)(c0 + ty + i) * rows + (r0 + tx)] = f2bf(tile[tx][ty + i]);
  } else {
    // pack mask int32 [row][2048] -> bits uint64 [row][32] (bit k = masked)
    const int row = bid - 12288;             // b*2048 + n
    const int w = t >> 6, lane = t & 63;
    const int* mrow = mask + (size_t)row * 2048;
#pragma unroll
    for (int it = 0; it < 8; ++it) {
      int key = it * 256 + w * 64 + lane;
      unsigned long long bal = __ballot(mrow[key] == 1);
      if (lane == 0) MP[(size_t)row * 32 + it * 4 + w] = bal;
    }
  }
}

// ---------------- GEMM: C[8192][N] = A[8192][1024] @ Bt[N][1024]^T ----------------
// EPI==0: LDS-restaged coalesced epilogue into Q (pre-scaled) / K [bh][2048][64],
//         V^T [bh][64][2048]. grid (24,64).  EPI==1: f32 out + bias. grid (8,64).
// Default block order (R9 showed default round-robin beats chunked XCD swizzle here).
template <int EPI>
__global__ __launch_bounds__(256) void k_gemm(
    const unsigned short* __restrict__ A, const unsigned short* __restrict__ Bt,
    unsigned short* __restrict__ Qo, unsigned short* __restrict__ Ko,
    unsigned short* __restrict__ Vo, float* __restrict__ Co,
    const float* __restrict__ bias) {
  // k-loop: As = Smem[0:8192), Bs = Smem[8192:16384). epilogue: Cs = Smem, stride 132.
  __shared__ __align__(16) short Smem[16896];   // 33792 B
  short* As = Smem;
  short* Bs = Smem + 8192;
  const int t = threadIdx.x;
  const int bn = blockIdx.x, bm = blockIdx.y;
  const int wid = t >> 6, lane = t & 63, g = lane >> 4, l15 = lane & 15;
  const int wr = wid >> 1, wc = wid & 1;
  f32x4 zero = {0.f, 0.f, 0.f, 0.f};
  f32x4 acc[4][4];
#pragma unroll
  for (int i = 0; i < 4; ++i)
#pragma unroll
    for (int j = 0; j < 4; ++j) acc[i][j] = zero;

  const char* Ab = (const char*)(A + (size_t)bm * 128 * 1024);  // row stride 2048B
  const char* Bb = (const char*)(Bt + (size_t)bn * 128 * 1024);

  for (int k0 = 0; k0 < 2048; k0 += 128) {   // K-step: 64 elems = 128 bytes
#pragma unroll
    for (int q = 0; q < 4; ++q) {
      int idx = t + q * 256, r = idx >> 3, c = idx & 7;
      int sw = (c * 16) ^ ((r & 7) << 4);
      gload16(Ab + (size_t)r * 2048 + k0 + sw, (char*)As + idx * 16);
      gload16(Bb + (size_t)r * 2048 + k0 + sw, (char*)Bs + idx * 16);
    }
    asm volatile("s_waitcnt vmcnt(0)" ::: "memory");
    __syncthreads();
#pragma unroll
    for (int ks = 0; ks < 2; ++ks) {
      bf16x8 a[4], b[4];
#pragma unroll
      for (int mi = 0; mi < 4; ++mi) a[mi] = ldsw(As, wr * 64 + mi * 16 + l15, ks * 32 + g * 8);
#pragma unroll
      for (int ni = 0; ni < 4; ++ni) b[ni] = ldsw(Bs, wc * 64 + ni * 16 + l15, ks * 32 + g * 8);
#pragma unroll
      for (int mi = 0; mi < 4; ++mi)
#pragma unroll
        for (int ni = 0; ni < 4; ++ni)
          acc[mi][ni] = __builtin_amdgcn_mfma_f32_16x16x32_bf16(a[mi], b[ni], acc[mi][ni], 0, 0, 0);
    }
    __syncthreads();   // also guards Smem reuse by the epilogue
  }

  if (EPI == 1) {
#pragma unroll
    for (int mi = 0; mi < 4; ++mi)
#pragma unroll
      for (int ni = 0; ni < 4; ++ni)
#pragma unroll
        for (int j = 0; j < 4; ++j) {
          int row = bm * 128 + wr * 64 + mi * 16 + g * 4 + j;
          int col = bn * 128 + wc * 64 + ni * 16 + l15;
          Co[(size_t)row * 1024 + col] = acc[mi][ni][j] + bias[col];
        }
    return;
  }

  // ---- EPI==0 coalesced epilogue ----
  const int s = bn >> 3;                 // 0=Q,1=K,2=V (uniform per block)
  const int h0 = (bn & 7) * 2;           // two heads in this tile
  const int bglob = (bm * 128) >> 11;    // batch (tile never straddles batches)
  const int n0 = (bm * 128) & 2047;

  if (s < 2) {
    const float qs = (s == 0) ? 0.18033688011112042f : 1.0f;  // 0.125*log2(e) for Q
    // stage Cs[row][col], stride 132 shorts
#pragma unroll
    for (int mi = 0; mi < 4; ++mi)
#pragma unroll
      for (int ni = 0; ni < 4; ++ni)
#pragma unroll
        for (int j = 0; j < 4; ++j)
          Smem[(wr * 64 + mi * 16 + g * 4 + j) * 132 + wc * 64 + ni * 16 + l15] =
              (short)f2bf(acc[mi][ni][j] * qs);
    __syncthreads();
    // copy out: thread -> row r, head-half hh; 64 shorts = 128B contiguous dest
    int r = t >> 1, hh = t & 1;
    unsigned short* dst = (s == 0 ? Qo : Ko) +
        (((size_t)(bglob * 16 + h0 + hh)) * 2048 + n0 + r) * 64;
    const short* src = Smem + r * 132 + hh * 64;
#pragma unroll
    for (int k = 0; k < 8; ++k) {
      uint2 a = *reinterpret_cast<const uint2*>(src + k * 8);
      uint2 b2 = *reinterpret_cast<const uint2*>(src + k * 8 + 4);
      uint4 w = {a.x, a.y, b2.x, b2.y};
      *reinterpret_cast<uint4*>(dst + k * 8) = w;
    }
  } else {
    // V: stage TRANSPOSED Cs_t[col][row] stride 132; per-fragment 4 j-rows adjacent -> b64
#pragma unroll
    for (int mi = 0; mi < 4; ++mi)
#pragma unroll
      for (int ni = 0; ni < 4; ++ni) {
        unsigned x0 = f2bf(acc[mi][ni][0]), x1 = f2bf(acc[mi][ni][1]);
        unsigned x2 = f2bf(acc[mi][ni][2]), x3 = f2bf(acc[mi][ni][3]);
        uint2 pk = {x0 | (x1 << 16), x2 | (x3 << 16)};
        int col = wc * 64 + ni * 16 + l15;
        int row = wr * 64 + mi * 16 + g * 4;
        *reinterpret_cast<uint2*>(Smem + col * 132 + row) = pk;
      }
    __syncthreads();
    // copy out: thread -> col c (head h, dim d), row-half seg; 64 shorts contiguous dest
    int c = t >> 1, seg = t & 1;
    int h = h0 + (c >> 6), d = c & 63;
    unsigned short* dst = Vo + ((size_t)(bglob * 16 + h) * 64 + d) * 2048 + n0 + seg * 64;
    const short* src = Smem + c * 132 + seg * 64;
#pragma unroll
    for (int k = 0; k < 8; ++k) {
      uint2 a = *reinterpret_cast<const uint2*>(src + k * 8);
      uint2 b2 = *reinterpret_cast<const uint2*>(src + k * 8 + 4);
      uint4 w = {a.x, a.y, b2.x, b2.y};
      *reinterpret_cast<uint4*>(dst + k * 8) = w;
    }
  }
}

// ---------------- flash attention ----------------
// grid 1024 (XCD-swizzled), 512 threads = 8 waves; QBLK=128, KV tile 64.
// Swapped QK^T: S^T = mfma(K, Q) -> lane (g,l15) holds 16 keys for q=l15.
// Key-half pipeline: {QK(2 frags) -> softmax -> pack -> PV} per 32-key half.
// K double-buffered; V SINGLE-buffered (staged at tile top, joined mid-tile with
// counted vmcnt + RAW s_barrier -- __syncthreads would drain vmcnt(0) and kill the
// K prefetch overlap). LDS = 32768B -> 4 blocks/CU. Loop ROLLED, runtime cb.
// Measured-rejected variants: ones-MFMA row-sum (R8 +15us), 32x32+permlane (R10
// +10us), 2x macro-unroll (R13 +12us), post-exp keep-mask + 4-way lp (R14 +2.5us).
__global__ __launch_bounds__(512, 8) void k_attn(
    const unsigned short* __restrict__ Q, const unsigned short* __restrict__ K,
    const unsigned short* __restrict__ Vt_g, const unsigned long long* __restrict__ pack,
    unsigned short* __restrict__ O) {
  __shared__ __align__(16) short Ks[2][64 * 64];    // 16KB
  __shared__ __align__(16) short Vt[64 * 64];       // 8KB  [d][key], single buffer
  __shared__ __align__(16) short Ps[8][16 * 32];    // 8KB per-wave P half [q][32key], swz
  const int bid0 = blockIdx.x;
  const int bid = (bid0 & 7) * 128 + (bid0 >> 3);   // XCD chunked swizzle (1024%8==0)
  const int qt = bid & 15, bh = bid >> 4;           // 16 q-tiles of 128
  const int b = bh >> 4;
  const int t = threadIdx.x, wid = t >> 6, lane = t & 63, g = lane >> 4, l15 = lane & 15;
  const char* Kb = (const char*)(K + (size_t)bh * (2048 * 64));     // row 128B
  const char* Vb = (const char*)(Vt_g + (size_t)bh * (64 * 2048));  // row 4096B
  const unsigned short* Qb = Q + (size_t)bh * (2048 * 64);

  // per-lane loop-invariant offsets
  const int sr = t >> 3, sc = t & 7;
  const int sw_src = (sc * 16) ^ ((sr & 7) << 4);
  char* PwB = (char*)&Ps[wid][0];                   // 16 rows x 64B
  const int ps_rd  = (l15 * 64 + g * 16) ^ ((l15 & 7) << 4);  // b128 read
  const int ps_wr0 = (l15 * 64 + g * 8) ^ ((l15 & 7) << 4);   // b64 write nf2=0
  // nf2=1 write offset == ps_wr0 ^ 32 (bit 5 untouched by +g*8, l15*64)

  // prologue: stage K tile 0 only (V(0) staged inside tile 0)
  gload16(Kb + (size_t)sr * 128 + sw_src, (char*)&Ks[0][0] + t * 16);
  // Q fragments to registers (B-operand of swapped QK^T): q = l15 row of wave's block
  const int qrow = qt * 128 + wid * 16 + l15;
  bf16x8 qf0 = *reinterpret_cast<const bf16x8*>(Qb + (size_t)qrow * 64 + g * 8);
  bf16x8 qf1 = *reinterpret_cast<const bf16x8*>(Qb + (size_t)qrow * 64 + 32 + g * 8);
  const unsigned long long* mrow = pack + ((size_t)b * 2048 + qrow) * 32;
  asm volatile("s_waitcnt vmcnt(0)" ::: "memory");
  __syncthreads();

  f32x4 zero = {0.f, 0.f, 0.f, 0.f};
  f32x4 oacc[4];
#pragma unroll
  for (int nf = 0; nf < 4; ++nf) oacc[nf] = zero;
  float lp = 0.f;                                   // partial row-sum for q=l15

  int cb = 0;
#pragma unroll 1
  for (int kt = 0; kt < 32; ++kt) {
    const int nb = cb ^ 1;
    // issue order matters for counted vmcnt: mask (oldest), V(t), K(t+1) (newest)
    unsigned long long mw = mrow[kt];
    gload16(Vb + (size_t)sr * 4096 + kt * 128 + sw_src, (char*)&Vt[0] + t * 16);
    if (kt + 1 < 32)
      gload16(Kb + (size_t)((kt + 1) * 64 + sr) * 128 + sw_src, (char*)&Ks[nb][0] + t * 16);
    unsigned mlo = (unsigned)mw >> (g * 4);         // key nf*16+g*4+j -> bit nf*16+j
    unsigned mhi = (unsigned)(mw >> 32) >> (g * 4);
#pragma unroll
    for (int kh = 0; kh < 2; ++kh) {                // 32-key half pipeline
      f32x4 sf[2] = {zero, zero};
      __builtin_amdgcn_s_setprio(1);
#pragma unroll
      for (int ds = 0; ds < 2; ++ds) {              // d-halves (contraction)
        bf16x8 qk = ds ? qf1 : qf0;
#pragma unroll
        for (int nf2 = 0; nf2 < 2; ++nf2) {
          bf16x8 kk = ldsw(&Ks[cb][0], (kh * 2 + nf2) * 16 + l15, ds * 32 + g * 8);
          sf[nf2] = __builtin_amdgcn_mfma_f32_16x16x32_bf16(kk, qk, sf[nf2], 0, 0, 0);
        }
      }
      __builtin_amdgcn_s_setprio(0);
      // softmax half: mask bits, exp2 (scores pre-scaled by 0.125*log2e), pack
      unsigned msrc = kh ? mhi : mlo;
#pragma unroll
      for (int nf2 = 0; nf2 < 2; ++nf2) {
        unsigned eu[4];
#pragma unroll
        for (int j = 0; j < 4; ++j) {
          float s = sf[nf2][j];
          if (msrc & (1u << (nf2 * 16 + j))) s = -1e30f;
          float e = __builtin_amdgcn_exp2f(s);
          lp += e;
          eu[j] = __builtin_bit_cast(unsigned, e);
        }
        uint2 pk;                                    // trunc-bf16 pack (P>=0)
        pk.x = __builtin_amdgcn_perm(eu[1], eu[0], 0x07060302);
        pk.y = __builtin_amdgcn_perm(eu[3], eu[2], 0x07060302);
        *reinterpret_cast<uint2*>(PwB + (nf2 ? (ps_wr0 ^ 32) : ps_wr0)) = pk;
      }
      if (kh == 0) {
        // mid-tile join: V(t) staged for all waves (K(t+1) stays in flight), Ps drained
        if (kt + 1 < 32) asm volatile("s_waitcnt vmcnt(1) lgkmcnt(0)" ::: "memory");
        else             asm volatile("s_waitcnt vmcnt(0) lgkmcnt(0)" ::: "memory");
        __builtin_amdgcn_s_barrier();
        __builtin_amdgcn_sched_barrier(0);
      } else {
        // within-wave Ps write->read ordering only
        asm volatile("s_waitcnt lgkmcnt(0)" ::: "memory");
        __builtin_amdgcn_sched_barrier(0);
      }
      // PV half: A = P[q][32 keys], B = Vt rows (d), k-dim = this key half
      bf16x8 ap = *reinterpret_cast<const bf16x8*>(PwB + ps_rd);
      __builtin_amdgcn_s_setprio(1);
#pragma unroll
      for (int nf = 0; nf < 4; ++nf) {
        bf16x8 bv = ldsw(&Vt[0], nf * 16 + l15, kh * 32 + g * 8);
        oacc[nf] = __builtin_amdgcn_mfma_f32_16x16x32_bf16(ap, bv, oacc[nf], 0, 0, 0);
      }
      __builtin_amdgcn_s_setprio(0);
    }
    // end-of-tile: K(t+1) staged (only outstanding load); also fences Vt reuse
    asm volatile("s_waitcnt vmcnt(0)" ::: "memory");
    __builtin_amdgcn_s_barrier();
    cb = nb;
  }

  // total row-sum for q=l15 (4 lanes per q across g-groups), redistribute inverse
  float l = lp;
  l += __shfl_xor(l, 16);
  l += __shfl_xor(l, 32);
  float invl = 1.0f / l;
  float inv[4];
#pragma unroll
  for (int j = 0; j < 4; ++j) inv[j] = __shfl(invl, g * 4 + j);  // lane l15==g*4+j

  // write attention output: ATT[b][n][h*64+d] bf16 ; O-tile: q=g*4+j, d=nf*16+l15
  const int h = bh & 15;
#pragma unroll
  for (int nf = 0; nf < 4; ++nf) {
#pragma unroll
    for (int j = 0; j < 4; ++j) {
      int qg = qt * 128 + wid * 16 + g * 4 + j;
      int d = nf * 16 + l15;
      O[((size_t)b * 2048 + qg) * 1024 + h * 64 + d] = f2bf(oacc[nf][j] * inv[j]);
    }
  }
}

extern "C" void kernel_launch(void* const* d_in, const int* in_sizes, int n_in,
                              void* d_out, int out_size, void* d_ws, size_t ws_size,
                              hipStream_t stream) {
  (void)in_sizes; (void)n_in; (void)out_size; (void)ws_size;
  const float* x = (const float*)d_in[0];
  const int* mask = (const int*)d_in[1];
  const float* Wqkv = (const float*)d_in[2];
  const float* Wout = (const float*)d_in[3];
  const float* bout = (const float*)d_in[4];
  float* out = (float*)d_out;

  unsigned short* ws = (unsigned short*)d_ws;
  unsigned short* Xb   = ws;                  // 8,388,608 elems
  unsigned short* Wq_t = Xb + 8388608;        // 3,145,728
  unsigned short* Wo_t = Wq_t + 3145728;      // 1,048,576
  unsigned short* Qa   = Wo_t + 1048576;      // 8,388,608 (pre-scaled by 0.125*log2e)
  unsigned short* Ka   = Qa + 8388608;        // 8,388,608
  unsigned short* Va   = Ka + 8388608;        // 8,388,608 (transposed [bh][64][2048])
  unsigned short* ATT  = Va + 8388608;        // 8,388,608
  unsigned long long* MP = (unsigned long long*)(ATT + 8388608);  // 2 MB

  k_prep<<<20480, 256, 0, stream>>>(x, Xb, Wqkv, Wq_t, Wout, Wo_t, mask, MP);
  k_gemm<0><<<dim3(24, 64), 256, 0, stream>>>(Xb, Wq_t, Qa, Ka, Va, nullptr, nullptr);
  k_attn<<<1024, 512, 0, stream>>>(Qa, Ka, Va, MP, ATT);
  k_gemm<1><<<dim3(8, 64), 256, 0, stream>>>(ATT, Wo_t, nullptr, nullptr, nullptr, out, bout);
}